// Round 1
// 324.516 us; speedup vs baseline: 1.1539x; 1.1539x over previous
//
#include <hip/hip_runtime.h>
#include <hip/hip_bf16.h>

// G2AAgent — ROUND 9: kSeq v4 (VALU diet: kill IEEE divisions).
//  Round-8 kSeq (199us) was VALU-bound (VALUBusy 67%, MfmaUtil 13%) with a 4x
//  gap vs the instruction-count model. Cause: fsigmoid/ftanh each contain a
//  C++ float division -> hipcc emits the full IEEE div sequence (~8 instr) x3
//  per GRU element. Fixes:
//   (a) fsigmoid/ftanh rewritten around v_rcp_f32 (__builtin_amdgcn_rcpf);
//       ftanh now branch-free: 1 - 2*rcp(1+e^{2x}).
//   (b) h_{t-1} kept in 8 registers (same thread computes same (row,col)
//       every step) -> removes 8 ds_read_u16 + 8 cvt per thread per step.
//   (c) bhh r/z gates folded into gS in phase 1 (bhh_n stays, it's inside r*()).
//   (d) blend as n + z*(h-n)  (fma form).
//  Same rcp fix applies to kStep (shared helpers), kGumbel, kAttn.

typedef __attribute__((ext_vector_type(8))) short short8;
typedef __attribute__((ext_vector_type(4))) float float4v;

#define BF2F(x) __bfloat162float(x)
typedef __hip_bfloat16 bf;

__device__ __forceinline__ float frcp(float x) {
  return __builtin_amdgcn_rcpf(x);
}
__device__ __forceinline__ float fsigmoid(float x) {
  return frcp(1.f + __expf(-x));
}
__device__ __forceinline__ float ftanh(float x) {
  // 1 - 2/(1+e^{2x}): saturates correctly (rcp(inf)=0 -> +1; e->0 -> -1)
  float e = __expf(2.f * x);
  return 1.f - 2.f * frcp(1.f + e);
}
__device__ __forceinline__ float rdv(const void* p, int i, int f) {
  return f ? ((const float*)p)[i] : BF2F(((const bf*)p)[i]);
}
__device__ __forceinline__ float upk(unsigned long long v, int s) {
  union { unsigned int i; float f; } x;
  x.i = ((unsigned int)((v >> s) & 0xffffULL)) << 16;
  return x.f;
}

// ---------------------------------------------------------------------------
static const int AO[23] = {
  0, 2097152, 4194304, 4685824, 4702208, 4702336, 4751488, 4800640, 4801024,
  4801408, 4899712, 4948864, 4949248, 4949632, 5047936, 5097088, 5097472,
  5097856, 5098368, 5098384, 5102480, 5106576, 5110160};
static const int AN[23] = {
  2097152, 2097152, 491520, 16384, 128, 49152, 49152, 384, 384, 98304, 49152,
  384, 384, 98304, 49152, 384, 384, 512, 2, 4096, 4096, 3584, 14};

struct CArgs {
  const void* src[23];
  int n[23];
  int off[23];
};

__global__ void kDetect(const unsigned short* __restrict__ p, int* flag) {
  __shared__ int s;
  if (threadIdx.x == 0) s = 0;
  __syncthreads();
  int hit = 0;
  for (int i = threadIdx.x; i < 4096; i += 1024) {
    int e = (p[i] >> 7) & 0xFF;
    if (e >= 0xC0) hit = 1;
  }
  if (hit) atomicOr(&s, 1);
  __syncthreads();
  if (threadIdx.x == 0) *flag = s;
}

__global__ void kConvert(CArgs a, const int* __restrict__ flag,
                         bf* __restrict__ arena) {
  const int b = blockIdx.y;
  const int n = a.n[b];
  const int f = *flag;
  bf* dst = arena + a.off[b];
  if (f) {
    const float* s = (const float*)a.src[b];
    for (int i = blockIdx.x * 256 + threadIdx.x; i < n; i += gridDim.x * 256)
      dst[i] = __float2bfloat16(s[i]);
  } else {
    const unsigned short* s = (const unsigned short*)a.src[b];
    unsigned short* d = (unsigned short*)dst;
    for (int i = blockIdx.x * 256 + threadIdx.x; i < n; i += gridDim.x * 256)
      d[i] = s[i];
  }
}

// ---------------------------------------------------------------------------
// kPrep: Wqk(64x128=[Wq;Wk]), W2p(16x256, rows 14/15 zero),
//        Wcb(2dir x 2logit x 128) from Wc arena.
__global__ void kPrep(const bf* __restrict__ Wq, const bf* __restrict__ Wk,
                      const bf* __restrict__ W2a, const bf* __restrict__ WcA,
                      bf* __restrict__ Wqk, bf* __restrict__ W2p,
                      bf* __restrict__ Wcb) {
  int idx = blockIdx.x * 256 + threadIdx.x;
  if (idx < 8192) {
    int r = idx >> 7, c = idx & 127;
    Wqk[idx] = (r < 32) ? Wq[r * 128 + c] : Wk[(r - 32) * 128 + c];
  }
  if (idx < 4096)
    W2p[idx] = (idx < 3584) ? W2a[idx] : __float2bfloat16(0.f);
  if (idx < 512) {
    int dir = idx >> 8, l = (idx >> 7) & 1, k = idx & 127;
    Wcb[idx] = WcA[l * 256 + dir * 128 + k];
  }
}

// ---------------------------------------------------------------------------
// kGemm: out[M x N](bf16) = A[M x 128] @ W[N x 128]^T + bias, optional relu.
__global__ __launch_bounds__(256) void kGemm(const bf* __restrict__ A,
                                             const bf* __restrict__ W,
                                             const bf* __restrict__ bias,
                                             bf* __restrict__ out,
                                             int N, int relu) {
  const int tid = threadIdx.x;
  const int wave = tid >> 6, lane = tid & 63;
  const int quad = lane >> 4, ci = lane & 15;
  const int mr = blockIdx.x * 64 + wave * 16;
  const int nbase = blockIdx.y * 64;
  const int ntiles = (N - nbase < 64) ? ((N - nbase) >> 4) : 4;

  float4v acc[4];
#pragma unroll
  for (int i = 0; i < 4; ++i) acc[i] = {0.f, 0.f, 0.f, 0.f};

#pragma unroll
  for (int ks = 0; ks < 4; ++ks) {
    short8 a = *(const short8*)(A + (size_t)(mr + ci) * 128 + ks * 32 + quad * 8);
    for (int nt = 0; nt < ntiles; ++nt) {
      short8 b = *(const short8*)(W + (size_t)(nbase + nt * 16 + ci) * 128 + ks * 32 + quad * 8);
      acc[nt] = __builtin_amdgcn_mfma_f32_16x16x32_bf16(a, b, acc[nt], 0, 0, 0);
    }
  }

  for (int nt = 0; nt < ntiles; ++nt) {
    int col = nbase + nt * 16 + ci;
    float bv = bias ? BF2F(bias[col]) : 0.f;
#pragma unroll
    for (int r = 0; r < 4; ++r) {
      int row = mr + quad * 4 + r;
      float v = acc[nt][r] + bv;
      if (relu) v = fmaxf(v, 0.f);
      out[(size_t)row * N + col] = __float2bfloat16(v);
    }
  }
}

// ---------------------------------------------------------------------------
// kStep: single GRU step (cell GRU only).
__global__ __launch_bounds__(256, 4) void kStep(
    const bf* __restrict__ Hp, const bf* __restrict__ Whh,
    const bf* __restrict__ G, int gld,
    const bf* __restrict__ bhh,
    bf* __restrict__ Ho, float* __restrict__ HcopyF) {
  const int half = blockIdx.z;
  const int tid = threadIdx.x;
  const int wave = tid >> 6, lane = tid & 63;
  const int quad = lane >> 4, ci = lane & 15;
  const int mr = blockIdx.x * 64 + wave * 16;

  float4v acc[12];
#pragma unroll
  for (int i = 0; i < 12; ++i) acc[i] = {0.f, 0.f, 0.f, 0.f};

#pragma unroll
  for (int ks = 0; ks < 4; ++ks) {
    short8 a = *(const short8*)(Hp + (size_t)(mr + ci) * 128 + ks * 32 + quad * 8);
#pragma unroll
    for (int g = 0; g < 3; ++g)
#pragma unroll
      for (int nt = 0; nt < 4; ++nt) {
        short8 b = *(const short8*)(Whh + (size_t)(g * 128 + half * 64 + nt * 16 + ci) * 128 + ks * 32 + quad * 8);
        acc[g * 4 + nt] = __builtin_amdgcn_mfma_f32_16x16x32_bf16(a, b, acc[g * 4 + nt], 0, 0, 0);
      }
  }

  float bR[4], bZ[4], bN[4];
#pragma unroll
  for (int nt = 0; nt < 4; ++nt) {
    int c = half * 64 + nt * 16 + ci;
    bR[nt] = BF2F(bhh[c]);
    bZ[nt] = BF2F(bhh[128 + c]);
    bN[nt] = BF2F(bhh[256 + c]);
  }

#pragma unroll
  for (int r = 0; r < 4; ++r) {
    int rr = mr + quad * 4 + r;
    const bf* gs = G + (size_t)rr * gld;
#pragma unroll
    for (int nt = 0; nt < 4; ++nt) {
      int c = half * 64 + nt * 16 + ci;
      float gr = BF2F(gs[c]), gz = BF2F(gs[128 + c]), gnn = BF2F(gs[256 + c]);
      float pre_r = acc[nt][r] + gr + bR[nt];
      float pre_z = acc[4 + nt][r] + gz + bZ[nt];
      float hn_   = acc[8 + nt][r] + bN[nt];
      float rg = fsigmoid(pre_r);
      float zg = fsigmoid(pre_z);
      float ng = ftanh(gnn + rg * hn_);
      float hp = BF2F(Hp[(size_t)rr * 128 + c]);
      float hv = ng + zg * (hp - ng);
      Ho[(size_t)rr * 128 + c] = __float2bfloat16(hv);
      if (HcopyF) HcopyF[(size_t)rr * 128 + c] = hv;
    }
  }
}

// ---------------------------------------------------------------------------
// kSeq v4: grid (1024, 2) = (env, dir), 256 thr = 4 waves (nh = 32-col quarter).
// Phase 1: gi GEMM retiled so each thread's self-gi C-layout cols == its step
//   epilogue cols -> self-gi lives in 24 VGPRs (fp32, +bih +bhh_{r,z} folded).
//   Nbr-gi packed 3-gates-per-u64 into sGiN. Phase 2: 24 persistent Whh
//   B-frags in VGPRs + Wc B-frag (lanes ci<2). Phase 3: 15 steps; h_{t-1}
//   kept in 8 regs (no LDS re-read); logits of h_{t-1} via one MFMA tile in
//   step t (wave nh0), tail MFMA for h_14; sL dumped once.
__global__ __launch_bounds__(256, 2) void kSeq(
    const bf* __restrict__ hrnn,
    const bf* __restrict__ Wih_f, const bf* __restrict__ Wih_b,
    const bf* __restrict__ Whh_f, const bf* __restrict__ Whh_b,
    const bf* __restrict__ bih_f, const bf* __restrict__ bih_b,
    const bf* __restrict__ bhh_f, const bf* __restrict__ bhh_b,
    const bf* __restrict__ Wcb, float* __restrict__ L) {
  __shared__ unsigned long long sGiN[16][130];  // [row][col] 3 bf16 gates  16.6 KB
  __shared__ bf sH[2][16][136];                 // h ping-pong               8.7 KB
  __shared__ float sL[16][15][2];               // logits                    1.9 KB

  const int env = blockIdx.x;
  const int dir = blockIdx.y;
  const int tid = threadIdx.x;
  const int wave = tid >> 6, lane = tid & 63;
  const int nh = wave;
  const int quad = lane >> 4, ci = lane & 15;
  const bf* Wih = dir ? Wih_b : Wih_f;
  const bf* Whh = dir ? Whh_b : Whh_f;
  const bf* bih = dir ? bih_b : bih_f;
  const bf* bhh = dir ? bhh_b : bhh_f;

  // ---- Phase 1: gi GEMM. Tiles: gate(3) x nt(2); B row = gate*128+nh*32+nt*16.
  float4v gS[6], gN[6];
#pragma unroll
  for (int i = 0; i < 6; ++i) { gS[i] = {0.f, 0.f, 0.f, 0.f}; gN[i] = {0.f, 0.f, 0.f, 0.f}; }
#pragma unroll
  for (int ks = 0; ks < 4; ++ks) {
    short8 a = *(const short8*)(hrnn + (size_t)(env * 16 + ci) * 128 + ks * 32 + quad * 8);
#pragma unroll
    for (int g = 0; g < 3; ++g)
#pragma unroll
      for (int nt = 0; nt < 2; ++nt) {
        const bf* wrow = Wih + (size_t)(g * 128 + nh * 32 + nt * 16 + ci) * 256 + ks * 32 + quad * 8;
        short8 bs = *(const short8*)(wrow);
        short8 bn = *(const short8*)(wrow + 128);
        gS[g * 2 + nt] = __builtin_amdgcn_mfma_f32_16x16x32_bf16(a, bs, gS[g * 2 + nt], 0, 0, 0);
        gN[g * 2 + nt] = __builtin_amdgcn_mfma_f32_16x16x32_bf16(a, bn, gN[g * 2 + nt], 0, 0, 0);
      }
  }
  // fold bih (+bhh for r,z gates) into self-gi (stays in regs); pack nbr-gi
#pragma unroll
  for (int g = 0; g < 3; ++g)
#pragma unroll
    for (int nt = 0; nt < 2; ++nt) {
      int c = g * 128 + nh * 32 + nt * 16 + ci;
      float bv = BF2F(bih[c]);
      if (g < 2) bv += BF2F(bhh[c]);
#pragma unroll
      for (int r = 0; r < 4; ++r) gS[g * 2 + nt][r] += bv;
    }
#pragma unroll
  for (int nt = 0; nt < 2; ++nt)
#pragma unroll
    for (int r = 0; r < 4; ++r) {
      unsigned long long pk = 0;
#pragma unroll
      for (int g = 0; g < 3; ++g) {
        bf b = __float2bfloat16(gN[g * 2 + nt][r]);
        pk |= ((unsigned long long)(*(unsigned short*)&b)) << (16 * g);
      }
      sGiN[quad * 4 + r][nh * 32 + nt * 16 + ci] = pk;
    }

  // zero h buffer 0
  {
    bf z = __float2bfloat16(0.f);
    bf* p = &sH[0][0][0];
    for (int i = tid; i < 16 * 136; i += 256) p[i] = z;
  }

  // ---- Phase 2: persistent Whh B-frags (96 VGPRs), Wc frag, constants ----
  short8 Bf[24];
#pragma unroll
  for (int g = 0; g < 3; ++g)
#pragma unroll
    for (int nt = 0; nt < 2; ++nt)
#pragma unroll
      for (int ks = 0; ks < 4; ++ks)
        Bf[(g * 2 + nt) * 4 + ks] =
            *(const short8*)(Whh + (size_t)(g * 128 + nh * 32 + nt * 16 + ci) * 128 + ks * 32 + quad * 8);

  short8 wcf[4];
#pragma unroll
  for (int ks = 0; ks < 4; ++ks) {
    if (ci < 2)
      wcf[ks] = *(const short8*)(Wcb + (size_t)(dir * 2 + ci) * 128 + ks * 32 + quad * 8);
    else
      wcf[ks] = short8{0, 0, 0, 0, 0, 0, 0, 0};
  }

  float bNc[2];
#pragma unroll
  for (int nt = 0; nt < 2; ++nt)
    bNc[nt] = BF2F(bhh[256 + nh * 32 + nt * 16 + ci]);

  // h_{t-1} for this thread's 8 output slots, kept in registers
  float hPrev[2][4];
#pragma unroll
  for (int nt = 0; nt < 2; ++nt)
#pragma unroll
    for (int r = 0; r < 4; ++r) hPrev[nt][r] = 0.f;

  __syncthreads();

  // ---- Phase 3: 15 steps ----
  for (int t = 0; t < 15; ++t) {
    const int cur = t & 1, nxt = cur ^ 1;
    const int m = dir ? (14 - t) : t;

    float4v acc[6];
#pragma unroll
    for (int i = 0; i < 6; ++i) acc[i] = {0.f, 0.f, 0.f, 0.f};
    float4v lacc = {0.f, 0.f, 0.f, 0.f};
#pragma unroll
    for (int ks = 0; ks < 4; ++ks) {
      short8 a = *(const short8*)&sH[cur][ci][ks * 32 + quad * 8];
#pragma unroll
      for (int tl = 0; tl < 6; ++tl)
        acc[tl] = __builtin_amdgcn_mfma_f32_16x16x32_bf16(a, Bf[tl * 4 + ks], acc[tl], 0, 0, 0);
      if (nh == 0)
        lacc = __builtin_amdgcn_mfma_f32_16x16x32_bf16(a, wcf[ks], lacc, 0, 0, 0);
    }
    if (nh == 0 && t > 0 && ci < 2) {
      int mp = dir ? (15 - t) : (t - 1);   // m of step t-1
#pragma unroll
      for (int r = 0; r < 4; ++r) sL[quad * 4 + r][mp][ci] = lacc[r];
    }

#pragma unroll
    for (int r_ = 0; r_ < 4; ++r_) {
      int row = quad * 4 + r_;
      int jr = m + ((m >= row) ? 1 : 0);
#pragma unroll
      for (int nt = 0; nt < 2; ++nt) {
        int c = nh * 32 + nt * 16 + ci;
        unsigned long long nb = sGiN[jr][c];
        float pre_r = acc[nt][r_] + gS[nt][r_] + upk(nb, 0);
        float pre_z = acc[2 + nt][r_] + gS[2 + nt][r_] + upk(nb, 16);
        float gnn   = gS[4 + nt][r_] + upk(nb, 32);
        float hn_   = acc[4 + nt][r_] + bNc[nt];
        float rg = fsigmoid(pre_r);
        float zg = fsigmoid(pre_z);
        float ng = ftanh(gnn + rg * hn_);
        float hp = hPrev[nt][r_];
        float hv = ng + zg * (hp - ng);
        hPrev[nt][r_] = hv;
        sH[nxt][row][c] = __float2bfloat16(hv);
      }
    }
    __syncthreads();
  }

  // tail: logits of h_14 (in sH[1])
  if (nh == 0) {
    float4v lacc = {0.f, 0.f, 0.f, 0.f};
#pragma unroll
    for (int ks = 0; ks < 4; ++ks) {
      short8 a = *(const short8*)&sH[1][ci][ks * 32 + quad * 8];
      lacc = __builtin_amdgcn_mfma_f32_16x16x32_bf16(a, wcf[ks], lacc, 0, 0, 0);
    }
    if (ci < 2) {
      int mf = dir ? 0 : 14;
#pragma unroll
      for (int r = 0; r < 4; ++r) sL[quad * 4 + r][mf][ci] = lacc[r];
    }
  }
  __syncthreads();

  for (int i = tid; i < 480; i += 256) {
    int row = i / 30, rem = i - row * 30;
    int mm = rem >> 1, l = rem & 1;
    L[(size_t)((env * 16 + row) * 15 + mm) * 4 + dir * 2 + l] = sL[row][mm][l];
  }
}

// ---------------------------------------------------------------------------
// kGumbel: hard_w = sigmoid(((l1+g1)-(l0+g0)) / TAU), TAU=0.5. Sums 2 dirs.
__global__ void kGumbel(const float* __restrict__ L, const void* __restrict__ guRaw,
                        const int* __restrict__ flag, const void* __restrict__ bcRaw,
                        float* __restrict__ hw) {
  int idx = blockIdx.x * 256 + threadIdx.x;
  if (idx >= 245760) return;
  const int f = *flag;
  const float* Lp = L + (size_t)idx * 4;
  float l0 = Lp[0] + Lp[2] + rdv(bcRaw, 0, f);
  float l1 = Lp[1] + Lp[3] + rdv(bcRaw, 1, f);
  float u0 = rdv(guRaw, idx * 2, f);
  float u1 = rdv(guRaw, idx * 2 + 1, f);
  float g0 = -__logf(-__logf(u0 + 1e-10f) + 1e-10f);
  float g1 = -__logf(-__logf(u1 + 1e-10f) + 1e-10f);
  float d = ((l1 + g1) - (l0 + g0)) * 2.0f;
  hw[idx] = fsigmoid(d);
}

// ---------------------------------------------------------------------------
// kAttn: per-env attention; writes agg (bf16, 16384x128). qk = 16384x64.
__global__ __launch_bounds__(256) void kAttn(
    const bf* __restrict__ h, const bf* __restrict__ qk,
    const float* __restrict__ hw, bf* __restrict__ aggB) {
  __shared__ float sh[16 * 132];
  __shared__ float sqk[16 * 64];
  __shared__ float shw[16 * 15];
  __shared__ float sw[16 * 16];
  int bb = blockIdx.x, tid = threadIdx.x;

  for (int i = tid; i < 2048; i += 256)
    sh[(i >> 7) * 132 + (i & 127)] = BF2F(h[(size_t)bb * 2048 + i]);
  for (int i = tid; i < 1024; i += 256)
    sqk[i] = BF2F(qk[(size_t)bb * 1024 + i]);
  for (int i = tid; i < 240; i += 256) shw[i] = hw[bb * 240 + i];
  __syncthreads();

  int a = tid >> 4, i = tid & 15;
  float s = -1e30f;
  if (i < 15) {
    int j = i + (i >= a);
    float d = 0.f;
#pragma unroll
    for (int c = 0; c < 32; ++c) d += sqk[a * 64 + c] * sqk[j * 64 + 32 + c];
    s = shw[a * 15 + i] * d * 0.17677669529663687f;
  }
  float mx = s;
#pragma unroll
  for (int d = 1; d < 16; d <<= 1) mx = fmaxf(mx, __shfl_xor(mx, d));
  float e = (i < 15) ? __expf(s - mx) : 0.f;
  float sum = e;
#pragma unroll
  for (int d = 1; d < 16; d <<= 1) sum += __shfl_xor(sum, d);
  float w = (i < 15) ? (e * frcp(sum)) * shw[a * 15 + i] : 0.f;
  sw[a * 16 + i] = w;
  __syncthreads();

  float ac[8] = {0, 0, 0, 0, 0, 0, 0, 0};
  for (int mm = 0; mm < 15; ++mm) {
    int jm = mm + (mm >= a);
    float wm = sw[a * 16 + mm];
    const float* shp = &sh[jm * 132 + i * 8];
    float4 h0 = *(const float4*)shp;
    float4 h1 = *(const float4*)(shp + 4);
    ac[0] += wm * h0.x; ac[1] += wm * h0.y; ac[2] += wm * h0.z; ac[3] += wm * h0.w;
    ac[4] += wm * h1.x; ac[5] += wm * h1.y; ac[6] += wm * h1.z; ac[7] += wm * h1.w;
  }
  short8 v;
#pragma unroll
  for (int d = 0; d < 8; ++d) {
    bf b = __float2bfloat16(ac[d]);
    v[d] = *(short*)&b;
  }
  *(short8*)(aggB + (size_t)(bb * 16 + a) * 128 + i * 8) = v;
}

// ---------------------------------------------------------------------------
// kGemmOut: out14[16384 x 14] (fp32) = [h_rnn, agg] @ W2p^T + b2.
__global__ __launch_bounds__(256) void kGemmOut(
    const bf* __restrict__ hrnn, const bf* __restrict__ aggB,
    const bf* __restrict__ W2p, const void* __restrict__ b2Raw,
    const int* __restrict__ flag, float* __restrict__ out) {
  const int tid = threadIdx.x;
  const int wave = tid >> 6, lane = tid & 63;
  const int quad = lane >> 4, ci = lane & 15;
  const int mr = blockIdx.x * 64 + wave * 16;
  const int f = *flag;

  float4v acc = {0.f, 0.f, 0.f, 0.f};
#pragma unroll
  for (int ks = 0; ks < 8; ++ks) {
    const bf* src = (ks < 4) ? hrnn : aggB;
    int k = (ks & 3) * 32 + quad * 8;
    short8 a = *(const short8*)(src + (size_t)(mr + ci) * 128 + k);
    short8 b = *(const short8*)(W2p + (size_t)ci * 256 + ks * 32 + quad * 8);
    acc = __builtin_amdgcn_mfma_f32_16x16x32_bf16(a, b, acc, 0, 0, 0);
  }

  if (ci < 14) {
    float bv = rdv(b2Raw, ci, f);
#pragma unroll
    for (int r = 0; r < 4; ++r)
      out[(size_t)(mr + quad * 4 + r) * 14 + ci] = acc[r] + bv;
  }
}

// ---------------------------------------------------------------------------
extern "C" void kernel_launch(void* const* d_in, const int* in_sizes, int n_in,
                              void* d_out, int out_size, void* d_ws, size_t ws_size,
                              hipStream_t stream) {
  const size_t OFF_ARENA = 0;          // bf16 arena; L (3.93MB) overlaps dead
                                       //   inputs+hidden [0, 8.38MB) after cell
  const size_t OFF_FLAG  = 10220544;
  const size_t OFF_A     = 10220800;   // x1+gi_c -> hw+agg
  const size_t OFF_WQK   = 26998016;   // 16 KB
  const size_t OFF_WCB   = 27014400;   // 1 KB
  const size_t OFF_W2P   = 27410944;   // 8 KB
  const size_t OFF_HRNN  = 27419136;   // 4 MB
  const size_t OFF_QK    = 31613440;   // 2 MB
  const size_t NEEDED    = 84042240;
  if (ws_size < NEEDED) return;
  if (n_in < 23 || in_sizes[0] != 2097152 || in_sizes[3] != 16384 ||
      in_sizes[5] != 49152 || in_sizes[9] != 98304 || in_sizes[17] != 512 ||
      in_sizes[19] != 4096 || in_sizes[21] != 3584 || out_size != 2326528)
    return;

  char* ws = (char*)d_ws;
  bf*    arena = (bf*)(ws + OFF_ARENA);
  float* L     = (float*)(ws + OFF_ARENA);  // 3.93 MB; valid after cell GRU
  int*   flag  = (int*)(ws + OFF_FLAG);
  bf*    x1    = (bf*)(ws + OFF_A);
  bf*    gi_c  = (bf*)(ws + OFF_A + 4194304);
  float* hw    = (float*)(ws + OFF_A);      // after kSeq (983 KB)
  bf*    aggB  = (bf*)(ws + OFF_A + 983040);
  bf*    Wqk   = (bf*)(ws + OFF_WQK);
  bf*    Wcb   = (bf*)(ws + OFF_WCB);
  bf*    W2p   = (bf*)(ws + OFF_W2P);
  bf*    hrnn  = (bf*)(ws + OFF_HRNN);
  bf*    qk    = (bf*)(ws + OFF_QK);

  float* out14 = (float*)d_out;
  float* outh  = (float*)d_out + 229376;

  kDetect<<<1, 1024, 0, stream>>>((const unsigned short*)d_in[0], flag);
  CArgs ca;
  for (int i = 0; i < 23; ++i) { ca.src[i] = d_in[i]; ca.n[i] = AN[i]; ca.off[i] = AO[i]; }
  kConvert<<<dim3(128, 23), 256, 0, stream>>>(ca, flag, arena);

  const bf* inputs = arena + AO[0];
  const bf* hidden = arena + AO[1];
  const bf* W1     = arena + AO[3];
  const bf* b1     = arena + AO[4];
  const bf* Wih_c  = arena + AO[5];
  const bf* Whh_c  = arena + AO[6];
  const bf* bih_c  = arena + AO[7];
  const bf* bhh_c  = arena + AO[8];
  const bf* Wih_f  = arena + AO[9];
  const bf* Whh_f  = arena + AO[10];
  const bf* bih_f  = arena + AO[11];
  const bf* bhh_f  = arena + AO[12];
  const bf* Wih_b  = arena + AO[13];
  const bf* Whh_b  = arena + AO[14];
  const bf* bih_b  = arena + AO[15];
  const bf* bhh_b  = arena + AO[16];
  const bf* WcA    = arena + AO[17];
  const bf* Wq     = arena + AO[19];
  const bf* Wk     = arena + AO[20];
  const bf* W2a    = arena + AO[21];

  kPrep<<<dim3(32), 256, 0, stream>>>(Wq, Wk, W2a, WcA, Wqk, W2p, Wcb);
  kGemm<<<dim3(256, 2), 256, 0, stream>>>(inputs, W1, b1, x1, 128, 1);
  kGemm<<<dim3(256, 6), 256, 0, stream>>>(x1, Wih_c, bih_c, gi_c, 384, 0);
  // cell GRU: h_rnn (bf16 + fp32 copy to d_out)
  kStep<<<dim3(256, 1, 2), 256, 0, stream>>>(hidden, Whh_c, gi_c, 384, bhh_c,
                                             hrnn, outh);
  // qk = h_rnn @ [Wq;Wk]^T  (16384 x 64)
  kGemm<<<dim3(256, 1), 256, 0, stream>>>(hrnn, Wqk, (const bf*)nullptr, qk, 64, 0);

  // fused gi-GEMM + 15-step bidirectional GRU -> L
  kSeq<<<dim3(1024, 2), 256, 0, stream>>>(hrnn, Wih_f, Wih_b, Whh_f, Whh_b,
                                          bih_f, bih_b, bhh_f, bhh_b, Wcb, L);

  kGumbel<<<dim3(960), 256, 0, stream>>>(L, d_in[2], flag, d_in[18], hw);
  kAttn<<<dim3(1024), 256, 0, stream>>>(hrnn, qk, hw, aggB);
  kGemmOut<<<dim3(256), 256, 0, stream>>>(hrnn, aggB, W2p, d_in[22], flag, out14);
}

// Round 2
// 311.912 us; speedup vs baseline: 1.2006x; 1.0404x over previous
//
#include <hip/hip_runtime.h>
#include <hip/hip_bf16.h>

// G2AAgent — ROUND 10: kSeq v5 (occupancy push: 8 waves x 16-col slices).
//  Round-9 kSeq (144us) was latency-bound: VALUBusy 47 + MfmaUtil 18, occ 21%.
//  Persistent regs (~200 unified: Bf 96 + wcf 16 + gS 24 + acc 28 + ...) cap
//  at 2 waves/SIMD. Fix: same work, 512-thr blocks, 8 waves each owning a
//  16-col slice -> Bf 48, gS 12, hPrev 4, acc 12; wcf moved to LDS (544B).
//  Peak ~105 regs -> __launch_bounds__(512,4) = 4 waves/SIMD (2x TLP).
//  MFMA count, LDS layout, arithmetic, and op order unchanged (absmax stable).

typedef __attribute__((ext_vector_type(8))) short short8;
typedef __attribute__((ext_vector_type(4))) float float4v;

#define BF2F(x) __bfloat162float(x)
typedef __hip_bfloat16 bf;

__device__ __forceinline__ float frcp(float x) {
  return __builtin_amdgcn_rcpf(x);
}
__device__ __forceinline__ float fsigmoid(float x) {
  return frcp(1.f + __expf(-x));
}
__device__ __forceinline__ float ftanh(float x) {
  // 1 - 2/(1+e^{2x}): saturates correctly (rcp(inf)=0 -> +1; e->0 -> -1)
  float e = __expf(2.f * x);
  return 1.f - 2.f * frcp(1.f + e);
}
__device__ __forceinline__ float rdv(const void* p, int i, int f) {
  return f ? ((const float*)p)[i] : BF2F(((const bf*)p)[i]);
}
__device__ __forceinline__ float upk(unsigned long long v, int s) {
  union { unsigned int i; float f; } x;
  x.i = ((unsigned int)((v >> s) & 0xffffULL)) << 16;
  return x.f;
}

// ---------------------------------------------------------------------------
static const int AO[23] = {
  0, 2097152, 4194304, 4685824, 4702208, 4702336, 4751488, 4800640, 4801024,
  4801408, 4899712, 4948864, 4949248, 4949632, 5047936, 5097088, 5097472,
  5097856, 5098368, 5098384, 5102480, 5106576, 5110160};
static const int AN[23] = {
  2097152, 2097152, 491520, 16384, 128, 49152, 49152, 384, 384, 98304, 49152,
  384, 384, 98304, 49152, 384, 384, 512, 2, 4096, 4096, 3584, 14};

struct CArgs {
  const void* src[23];
  int n[23];
  int off[23];
};

__global__ void kDetect(const unsigned short* __restrict__ p, int* flag) {
  __shared__ int s;
  if (threadIdx.x == 0) s = 0;
  __syncthreads();
  int hit = 0;
  for (int i = threadIdx.x; i < 4096; i += 1024) {
    int e = (p[i] >> 7) & 0xFF;
    if (e >= 0xC0) hit = 1;
  }
  if (hit) atomicOr(&s, 1);
  __syncthreads();
  if (threadIdx.x == 0) *flag = s;
}

__global__ void kConvert(CArgs a, const int* __restrict__ flag,
                         bf* __restrict__ arena) {
  const int b = blockIdx.y;
  const int n = a.n[b];
  const int f = *flag;
  bf* dst = arena + a.off[b];
  if (f) {
    const float* s = (const float*)a.src[b];
    for (int i = blockIdx.x * 256 + threadIdx.x; i < n; i += gridDim.x * 256)
      dst[i] = __float2bfloat16(s[i]);
  } else {
    const unsigned short* s = (const unsigned short*)a.src[b];
    unsigned short* d = (unsigned short*)dst;
    for (int i = blockIdx.x * 256 + threadIdx.x; i < n; i += gridDim.x * 256)
      d[i] = s[i];
  }
}

// ---------------------------------------------------------------------------
// kPrep: Wqk(64x128=[Wq;Wk]), W2p(16x256, rows 14/15 zero),
//        Wcb(2dir x 2logit x 128) from Wc arena.
__global__ void kPrep(const bf* __restrict__ Wq, const bf* __restrict__ Wk,
                      const bf* __restrict__ W2a, const bf* __restrict__ WcA,
                      bf* __restrict__ Wqk, bf* __restrict__ W2p,
                      bf* __restrict__ Wcb) {
  int idx = blockIdx.x * 256 + threadIdx.x;
  if (idx < 8192) {
    int r = idx >> 7, c = idx & 127;
    Wqk[idx] = (r < 32) ? Wq[r * 128 + c] : Wk[(r - 32) * 128 + c];
  }
  if (idx < 4096)
    W2p[idx] = (idx < 3584) ? W2a[idx] : __float2bfloat16(0.f);
  if (idx < 512) {
    int dir = idx >> 8, l = (idx >> 7) & 1, k = idx & 127;
    Wcb[idx] = WcA[l * 256 + dir * 128 + k];
  }
}

// ---------------------------------------------------------------------------
// kGemm: out[M x N](bf16) = A[M x 128] @ W[N x 128]^T + bias, optional relu.
__global__ __launch_bounds__(256) void kGemm(const bf* __restrict__ A,
                                             const bf* __restrict__ W,
                                             const bf* __restrict__ bias,
                                             bf* __restrict__ out,
                                             int N, int relu) {
  const int tid = threadIdx.x;
  const int wave = tid >> 6, lane = tid & 63;
  const int quad = lane >> 4, ci = lane & 15;
  const int mr = blockIdx.x * 64 + wave * 16;
  const int nbase = blockIdx.y * 64;
  const int ntiles = (N - nbase < 64) ? ((N - nbase) >> 4) : 4;

  float4v acc[4];
#pragma unroll
  for (int i = 0; i < 4; ++i) acc[i] = {0.f, 0.f, 0.f, 0.f};

#pragma unroll
  for (int ks = 0; ks < 4; ++ks) {
    short8 a = *(const short8*)(A + (size_t)(mr + ci) * 128 + ks * 32 + quad * 8);
    for (int nt = 0; nt < ntiles; ++nt) {
      short8 b = *(const short8*)(W + (size_t)(nbase + nt * 16 + ci) * 128 + ks * 32 + quad * 8);
      acc[nt] = __builtin_amdgcn_mfma_f32_16x16x32_bf16(a, b, acc[nt], 0, 0, 0);
    }
  }

  for (int nt = 0; nt < ntiles; ++nt) {
    int col = nbase + nt * 16 + ci;
    float bv = bias ? BF2F(bias[col]) : 0.f;
#pragma unroll
    for (int r = 0; r < 4; ++r) {
      int row = mr + quad * 4 + r;
      float v = acc[nt][r] + bv;
      if (relu) v = fmaxf(v, 0.f);
      out[(size_t)row * N + col] = __float2bfloat16(v);
    }
  }
}

// ---------------------------------------------------------------------------
// kStep: single GRU step (cell GRU only).
__global__ __launch_bounds__(256, 4) void kStep(
    const bf* __restrict__ Hp, const bf* __restrict__ Whh,
    const bf* __restrict__ G, int gld,
    const bf* __restrict__ bhh,
    bf* __restrict__ Ho, float* __restrict__ HcopyF) {
  const int half = blockIdx.z;
  const int tid = threadIdx.x;
  const int wave = tid >> 6, lane = tid & 63;
  const int quad = lane >> 4, ci = lane & 15;
  const int mr = blockIdx.x * 64 + wave * 16;

  float4v acc[12];
#pragma unroll
  for (int i = 0; i < 12; ++i) acc[i] = {0.f, 0.f, 0.f, 0.f};

#pragma unroll
  for (int ks = 0; ks < 4; ++ks) {
    short8 a = *(const short8*)(Hp + (size_t)(mr + ci) * 128 + ks * 32 + quad * 8);
#pragma unroll
    for (int g = 0; g < 3; ++g)
#pragma unroll
      for (int nt = 0; nt < 4; ++nt) {
        short8 b = *(const short8*)(Whh + (size_t)(g * 128 + half * 64 + nt * 16 + ci) * 128 + ks * 32 + quad * 8);
        acc[g * 4 + nt] = __builtin_amdgcn_mfma_f32_16x16x32_bf16(a, b, acc[g * 4 + nt], 0, 0, 0);
      }
  }

  float bR[4], bZ[4], bN[4];
#pragma unroll
  for (int nt = 0; nt < 4; ++nt) {
    int c = half * 64 + nt * 16 + ci;
    bR[nt] = BF2F(bhh[c]);
    bZ[nt] = BF2F(bhh[128 + c]);
    bN[nt] = BF2F(bhh[256 + c]);
  }

#pragma unroll
  for (int r = 0; r < 4; ++r) {
    int rr = mr + quad * 4 + r;
    const bf* gs = G + (size_t)rr * gld;
#pragma unroll
    for (int nt = 0; nt < 4; ++nt) {
      int c = half * 64 + nt * 16 + ci;
      float gr = BF2F(gs[c]), gz = BF2F(gs[128 + c]), gnn = BF2F(gs[256 + c]);
      float pre_r = acc[nt][r] + gr + bR[nt];
      float pre_z = acc[4 + nt][r] + gz + bZ[nt];
      float hn_   = acc[8 + nt][r] + bN[nt];
      float rg = fsigmoid(pre_r);
      float zg = fsigmoid(pre_z);
      float ng = ftanh(gnn + rg * hn_);
      float hp = BF2F(Hp[(size_t)rr * 128 + c]);
      float hv = ng + zg * (hp - ng);
      Ho[(size_t)rr * 128 + c] = __float2bfloat16(hv);
      if (HcopyF) HcopyF[(size_t)rr * 128 + c] = hv;
    }
  }
}

// ---------------------------------------------------------------------------
// kSeq v5: grid (1024, 2) = (env, dir), 512 thr = 8 waves (nh = 16-col slice).
// Per-wave state halved vs v4: Bf 12 frags (48 VGPR), gS[3] (12), hPrev (4),
// acc[3] (12); Wc frag read from LDS (sWc, 544B) by wave 0 only. Peak ~105
// regs -> 4 waves/SIMD (16 waves/CU). Work, arithmetic, and op order
// identical to v4; only the wave->column mapping changed.
__global__ __launch_bounds__(512, 4) void kSeq(
    const bf* __restrict__ hrnn,
    const bf* __restrict__ Wih_f, const bf* __restrict__ Wih_b,
    const bf* __restrict__ Whh_f, const bf* __restrict__ Whh_b,
    const bf* __restrict__ bih_f, const bf* __restrict__ bih_b,
    const bf* __restrict__ bhh_f, const bf* __restrict__ bhh_b,
    const bf* __restrict__ Wcb, float* __restrict__ L) {
  __shared__ unsigned long long sGiN[16][130];  // [row][col] 3 bf16 gates  16.6 KB
  __shared__ bf sH[2][16][136];                 // h ping-pong               8.7 KB
  __shared__ float sL[16][15][2];               // logits                    1.9 KB
  __shared__ bf sWc[2][136];                    // Wc rows for this dir      544 B

  const int env = blockIdx.x;
  const int dir = blockIdx.y;
  const int tid = threadIdx.x;
  const int wave = tid >> 6, lane = tid & 63;
  const int nh = wave;                          // 16-col slice index [0,8)
  const int quad = lane >> 4, ci = lane & 15;
  const bf* Wih = dir ? Wih_b : Wih_f;
  const bf* Whh = dir ? Whh_b : Whh_f;
  const bf* bih = dir ? bih_b : bih_f;
  const bf* bhh = dir ? bhh_b : bhh_f;
  const int cb = nh * 16 + ci;                  // this thread's column

  // ---- Phase 1: gi GEMM. Tiles: gate(3); B row = gate*128 + nh*16.
  float4v gS[3], gN[3];
#pragma unroll
  for (int i = 0; i < 3; ++i) { gS[i] = {0.f, 0.f, 0.f, 0.f}; gN[i] = {0.f, 0.f, 0.f, 0.f}; }
#pragma unroll
  for (int ks = 0; ks < 4; ++ks) {
    short8 a = *(const short8*)(hrnn + (size_t)(env * 16 + ci) * 128 + ks * 32 + quad * 8);
#pragma unroll
    for (int g = 0; g < 3; ++g) {
      const bf* wrow = Wih + (size_t)(g * 128 + nh * 16 + ci) * 256 + ks * 32 + quad * 8;
      short8 bs = *(const short8*)(wrow);
      short8 bn = *(const short8*)(wrow + 128);
      gS[g] = __builtin_amdgcn_mfma_f32_16x16x32_bf16(a, bs, gS[g], 0, 0, 0);
      gN[g] = __builtin_amdgcn_mfma_f32_16x16x32_bf16(a, bn, gN[g], 0, 0, 0);
    }
  }
  // fold bih (+bhh for r,z gates) into self-gi (stays in regs); pack nbr-gi
#pragma unroll
  for (int g = 0; g < 3; ++g) {
    int c = g * 128 + cb;
    float bv = BF2F(bih[c]);
    if (g < 2) bv += BF2F(bhh[c]);
#pragma unroll
    for (int r = 0; r < 4; ++r) gS[g][r] += bv;
  }
#pragma unroll
  for (int r = 0; r < 4; ++r) {
    unsigned long long pk = 0;
#pragma unroll
    for (int g = 0; g < 3; ++g) {
      bf b = __float2bfloat16(gN[g][r]);
      pk |= ((unsigned long long)(*(unsigned short*)&b)) << (16 * g);
    }
    sGiN[quad * 4 + r][cb] = pk;
  }

  // zero h buffer 0; fill sWc
  {
    bf z = __float2bfloat16(0.f);
    bf* p = &sH[0][0][0];
    for (int i = tid; i < 16 * 136; i += 512) p[i] = z;
    if (tid < 256)
      sWc[tid >> 7][tid & 127] = Wcb[(dir * 2 + (tid >> 7)) * 128 + (tid & 127)];
  }

  // ---- Phase 2: persistent Whh B-frags (48 VGPRs), constants ----
  short8 Bf[12];
#pragma unroll
  for (int g = 0; g < 3; ++g)
#pragma unroll
    for (int ks = 0; ks < 4; ++ks)
      Bf[g * 4 + ks] =
          *(const short8*)(Whh + (size_t)(g * 128 + nh * 16 + ci) * 128 + ks * 32 + quad * 8);

  float bNc = BF2F(bhh[256 + cb]);

  // h_{t-1} for this thread's 4 output slots, kept in registers
  float hPrev[4];
#pragma unroll
  for (int r = 0; r < 4; ++r) hPrev[r] = 0.f;

  __syncthreads();

  // ---- Phase 3: 15 steps ----
  for (int t = 0; t < 15; ++t) {
    const int cur = t & 1, nxt = cur ^ 1;
    const int m = dir ? (14 - t) : t;

    float4v acc[3];
#pragma unroll
    for (int i = 0; i < 3; ++i) acc[i] = {0.f, 0.f, 0.f, 0.f};
    float4v lacc = {0.f, 0.f, 0.f, 0.f};
#pragma unroll
    for (int ks = 0; ks < 4; ++ks) {
      short8 a = *(const short8*)&sH[cur][ci][ks * 32 + quad * 8];
#pragma unroll
      for (int g = 0; g < 3; ++g)
        acc[g] = __builtin_amdgcn_mfma_f32_16x16x32_bf16(a, Bf[g * 4 + ks], acc[g], 0, 0, 0);
      if (nh == 0) {
        // B rows >=2 are garbage (row ci&1) -> only output cols 0,1 are
        // consumed; MFMA col j depends only on B row j, so this is safe.
        short8 wv = *(const short8*)&sWc[ci & 1][ks * 32 + quad * 8];
        lacc = __builtin_amdgcn_mfma_f32_16x16x32_bf16(a, wv, lacc, 0, 0, 0);
      }
    }
    if (nh == 0 && t > 0 && ci < 2) {
      int mp = dir ? (15 - t) : (t - 1);   // m of step t-1
#pragma unroll
      for (int r = 0; r < 4; ++r) sL[quad * 4 + r][mp][ci] = lacc[r];
    }

#pragma unroll
    for (int r_ = 0; r_ < 4; ++r_) {
      int row = quad * 4 + r_;
      int jr = m + ((m >= row) ? 1 : 0);
      unsigned long long nb = sGiN[jr][cb];
      float pre_r = acc[0][r_] + gS[0][r_] + upk(nb, 0);
      float pre_z = acc[1][r_] + gS[1][r_] + upk(nb, 16);
      float gnn   = gS[2][r_] + upk(nb, 32);
      float hn_   = acc[2][r_] + bNc;
      float rg = fsigmoid(pre_r);
      float zg = fsigmoid(pre_z);
      float ng = ftanh(gnn + rg * hn_);
      float hp = hPrev[r_];
      float hv = ng + zg * (hp - ng);
      hPrev[r_] = hv;
      sH[nxt][row][cb] = __float2bfloat16(hv);
    }
    __syncthreads();
  }

  // tail: logits of h_14 (in sH[1])
  if (nh == 0) {
    float4v lacc = {0.f, 0.f, 0.f, 0.f};
#pragma unroll
    for (int ks = 0; ks < 4; ++ks) {
      short8 a = *(const short8*)&sH[1][ci][ks * 32 + quad * 8];
      short8 wv = *(const short8*)&sWc[ci & 1][ks * 32 + quad * 8];
      lacc = __builtin_amdgcn_mfma_f32_16x16x32_bf16(a, wv, lacc, 0, 0, 0);
    }
    if (ci < 2) {
      int mf = dir ? 0 : 14;
#pragma unroll
      for (int r = 0; r < 4; ++r) sL[quad * 4 + r][mf][ci] = lacc[r];
    }
  }
  __syncthreads();

  for (int i = tid; i < 480; i += 512) {
    int row = i / 30, rem = i - row * 30;
    int mm = rem >> 1, l = rem & 1;
    L[(size_t)((env * 16 + row) * 15 + mm) * 4 + dir * 2 + l] = sL[row][mm][l];
  }
}

// ---------------------------------------------------------------------------
// kGumbel: hard_w = sigmoid(((l1+g1)-(l0+g0)) / TAU), TAU=0.5. Sums 2 dirs.
__global__ void kGumbel(const float* __restrict__ L, const void* __restrict__ guRaw,
                        const int* __restrict__ flag, const void* __restrict__ bcRaw,
                        float* __restrict__ hw) {
  int idx = blockIdx.x * 256 + threadIdx.x;
  if (idx >= 245760) return;
  const int f = *flag;
  const float* Lp = L + (size_t)idx * 4;
  float l0 = Lp[0] + Lp[2] + rdv(bcRaw, 0, f);
  float l1 = Lp[1] + Lp[3] + rdv(bcRaw, 1, f);
  float u0 = rdv(guRaw, idx * 2, f);
  float u1 = rdv(guRaw, idx * 2 + 1, f);
  float g0 = -__logf(-__logf(u0 + 1e-10f) + 1e-10f);
  float g1 = -__logf(-__logf(u1 + 1e-10f) + 1e-10f);
  float d = ((l1 + g1) - (l0 + g0)) * 2.0f;
  hw[idx] = fsigmoid(d);
}

// ---------------------------------------------------------------------------
// kAttn: per-env attention; writes agg (bf16, 16384x128). qk = 16384x64.
__global__ __launch_bounds__(256) void kAttn(
    const bf* __restrict__ h, const bf* __restrict__ qk,
    const float* __restrict__ hw, bf* __restrict__ aggB) {
  __shared__ float sh[16 * 132];
  __shared__ float sqk[16 * 64];
  __shared__ float shw[16 * 15];
  __shared__ float sw[16 * 16];
  int bb = blockIdx.x, tid = threadIdx.x;

  for (int i = tid; i < 2048; i += 256)
    sh[(i >> 7) * 132 + (i & 127)] = BF2F(h[(size_t)bb * 2048 + i]);
  for (int i = tid; i < 1024; i += 256)
    sqk[i] = BF2F(qk[(size_t)bb * 1024 + i]);
  for (int i = tid; i < 240; i += 256) shw[i] = hw[bb * 240 + i];
  __syncthreads();

  int a = tid >> 4, i = tid & 15;
  float s = -1e30f;
  if (i < 15) {
    int j = i + (i >= a);
    float d = 0.f;
#pragma unroll
    for (int c = 0; c < 32; ++c) d += sqk[a * 64 + c] * sqk[j * 64 + 32 + c];
    s = shw[a * 15 + i] * d * 0.17677669529663687f;
  }
  float mx = s;
#pragma unroll
  for (int d = 1; d < 16; d <<= 1) mx = fmaxf(mx, __shfl_xor(mx, d));
  float e = (i < 15) ? __expf(s - mx) : 0.f;
  float sum = e;
#pragma unroll
  for (int d = 1; d < 16; d <<= 1) sum += __shfl_xor(sum, d);
  float w = (i < 15) ? (e * frcp(sum)) * shw[a * 15 + i] : 0.f;
  sw[a * 16 + i] = w;
  __syncthreads();

  float ac[8] = {0, 0, 0, 0, 0, 0, 0, 0};
  for (int mm = 0; mm < 15; ++mm) {
    int jm = mm + (mm >= a);
    float wm = sw[a * 16 + mm];
    const float* shp = &sh[jm * 132 + i * 8];
    float4 h0 = *(const float4*)shp;
    float4 h1 = *(const float4*)(shp + 4);
    ac[0] += wm * h0.x; ac[1] += wm * h0.y; ac[2] += wm * h0.z; ac[3] += wm * h0.w;
    ac[4] += wm * h1.x; ac[5] += wm * h1.y; ac[6] += wm * h1.z; ac[7] += wm * h1.w;
  }
  short8 v;
#pragma unroll
  for (int d = 0; d < 8; ++d) {
    bf b = __float2bfloat16(ac[d]);
    v[d] = *(short*)&b;
  }
  *(short8*)(aggB + (size_t)(bb * 16 + a) * 128 + i * 8) = v;
}

// ---------------------------------------------------------------------------
// kGemmOut: out14[16384 x 14] (fp32) = [h_rnn, agg] @ W2p^T + b2.
__global__ __launch_bounds__(256) void kGemmOut(
    const bf* __restrict__ hrnn, const bf* __restrict__ aggB,
    const bf* __restrict__ W2p, const void* __restrict__ b2Raw,
    const int* __restrict__ flag, float* __restrict__ out) {
  const int tid = threadIdx.x;
  const int wave = tid >> 6, lane = tid & 63;
  const int quad = lane >> 4, ci = lane & 15;
  const int mr = blockIdx.x * 64 + wave * 16;
  const int f = *flag;

  float4v acc = {0.f, 0.f, 0.f, 0.f};
#pragma unroll
  for (int ks = 0; ks < 8; ++ks) {
    const bf* src = (ks < 4) ? hrnn : aggB;
    int k = (ks & 3) * 32 + quad * 8;
    short8 a = *(const short8*)(src + (size_t)(mr + ci) * 128 + k);
    short8 b = *(const short8*)(W2p + (size_t)ci * 256 + ks * 32 + quad * 8);
    acc = __builtin_amdgcn_mfma_f32_16x16x32_bf16(a, b, acc, 0, 0, 0);
  }

  if (ci < 14) {
    float bv = rdv(b2Raw, ci, f);
#pragma unroll
    for (int r = 0; r < 4; ++r)
      out[(size_t)(mr + quad * 4 + r) * 14 + ci] = acc[r] + bv;
  }
}

// ---------------------------------------------------------------------------
extern "C" void kernel_launch(void* const* d_in, const int* in_sizes, int n_in,
                              void* d_out, int out_size, void* d_ws, size_t ws_size,
                              hipStream_t stream) {
  const size_t OFF_ARENA = 0;          // bf16 arena; L (3.93MB) overlaps dead
                                       //   inputs+hidden [0, 8.38MB) after cell
  const size_t OFF_FLAG  = 10220544;
  const size_t OFF_A     = 10220800;   // x1+gi_c -> hw+agg
  const size_t OFF_WQK   = 26998016;   // 16 KB
  const size_t OFF_WCB   = 27014400;   // 1 KB
  const size_t OFF_W2P   = 27410944;   // 8 KB
  const size_t OFF_HRNN  = 27419136;   // 4 MB
  const size_t OFF_QK    = 31613440;   // 2 MB
  const size_t NEEDED    = 84042240;
  if (ws_size < NEEDED) return;
  if (n_in < 23 || in_sizes[0] != 2097152 || in_sizes[3] != 16384 ||
      in_sizes[5] != 49152 || in_sizes[9] != 98304 || in_sizes[17] != 512 ||
      in_sizes[19] != 4096 || in_sizes[21] != 3584 || out_size != 2326528)
    return;

  char* ws = (char*)d_ws;
  bf*    arena = (bf*)(ws + OFF_ARENA);
  float* L     = (float*)(ws + OFF_ARENA);  // 3.93 MB; valid after cell GRU
  int*   flag  = (int*)(ws + OFF_FLAG);
  bf*    x1    = (bf*)(ws + OFF_A);
  bf*    gi_c  = (bf*)(ws + OFF_A + 4194304);
  float* hw    = (float*)(ws + OFF_A);      // after kSeq (983 KB)
  bf*    aggB  = (bf*)(ws + OFF_A + 983040);
  bf*    Wqk   = (bf*)(ws + OFF_WQK);
  bf*    Wcb   = (bf*)(ws + OFF_WCB);
  bf*    W2p   = (bf*)(ws + OFF_W2P);
  bf*    hrnn  = (bf*)(ws + OFF_HRNN);
  bf*    qk    = (bf*)(ws + OFF_QK);

  float* out14 = (float*)d_out;
  float* outh  = (float*)d_out + 229376;

  kDetect<<<1, 1024, 0, stream>>>((const unsigned short*)d_in[0], flag);
  CArgs ca;
  for (int i = 0; i < 23; ++i) { ca.src[i] = d_in[i]; ca.n[i] = AN[i]; ca.off[i] = AO[i]; }
  kConvert<<<dim3(128, 23), 256, 0, stream>>>(ca, flag, arena);

  const bf* inputs = arena + AO[0];
  const bf* hidden = arena + AO[1];
  const bf* W1     = arena + AO[3];
  const bf* b1     = arena + AO[4];
  const bf* Wih_c  = arena + AO[5];
  const bf* Whh_c  = arena + AO[6];
  const bf* bih_c  = arena + AO[7];
  const bf* bhh_c  = arena + AO[8];
  const bf* Wih_f  = arena + AO[9];
  const bf* Whh_f  = arena + AO[10];
  const bf* bih_f  = arena + AO[11];
  const bf* bhh_f  = arena + AO[12];
  const bf* Wih_b  = arena + AO[13];
  const bf* Whh_b  = arena + AO[14];
  const bf* bih_b  = arena + AO[15];
  const bf* bhh_b  = arena + AO[16];
  const bf* WcA    = arena + AO[17];
  const bf* Wq     = arena + AO[19];
  const bf* Wk     = arena + AO[20];
  const bf* W2a    = arena + AO[21];

  kPrep<<<dim3(32), 256, 0, stream>>>(Wq, Wk, W2a, WcA, Wqk, W2p, Wcb);
  kGemm<<<dim3(256, 2), 256, 0, stream>>>(inputs, W1, b1, x1, 128, 1);
  kGemm<<<dim3(256, 6), 256, 0, stream>>>(x1, Wih_c, bih_c, gi_c, 384, 0);
  // cell GRU: h_rnn (bf16 + fp32 copy to d_out)
  kStep<<<dim3(256, 1, 2), 256, 0, stream>>>(hidden, Whh_c, gi_c, 384, bhh_c,
                                             hrnn, outh);
  // qk = h_rnn @ [Wq;Wk]^T  (16384 x 64)
  kGemm<<<dim3(256, 1), 256, 0, stream>>>(hrnn, Wqk, (const bf*)nullptr, qk, 64, 0);

  // fused gi-GEMM + 15-step bidirectional GRU -> L
  kSeq<<<dim3(1024, 2), 512, 0, stream>>>(hrnn, Wih_f, Wih_b, Whh_f, Whh_b,
                                          bih_f, bih_b, bhh_f, bhh_b, Wcb, L);

  kGumbel<<<dim3(960), 256, 0, stream>>>(L, d_in[2], flag, d_in[18], hw);
  kAttn<<<dim3(1024), 256, 0, stream>>>(hrnn, qk, hw, aggB);
  kGemmOut<<<dim3(256), 256, 0, stream>>>(hrnn, aggB, W2p, d_in[22], flag, out14);
}

// Round 3
// 280.548 us; speedup vs baseline: 1.3348x; 1.1118x over previous
//
#include <hip/hip_runtime.h>
#include <hip/hip_bf16.h>

// G2AAgent — ROUND 11: kSeq v6 (operand-swap) + launch diet.
//  R10 kSeq (128.7us): occ 41% as predicted but LDS bank conflicts 2.5x'd to
//  4.98M — traced to the epilogue's sH scatter-writes (rows 8 apart alias the
//  same bank at any 16B-multiple stride; padding can't fix). Fix: SWAP the
//  MFMA operands (A/B frags have identical lane layouts) -> D[hcol][batch]:
//  each thread owns batch=ci and 4 CONSECUTIVE hcols, so:
//   - sH write = one aligned ds_write_b64 (bank-verified conflict-free);
//   - sGiN read = 2x b128 at wave-uniform addrs (broadcast) vs 4x b64;
//   - jr computed once per thread per step. Same loads, same math order ->
//     bit-identical output.
//  Launch diet (11 -> 8): kPrep folded into kConvert (extra grid-y, reads
//  d_in via rdv); qk-GEMM + kGumbel fused into kAttn (qk = in-block MFMA,
//  hw only consumed there); kConvert vectorized short8/float4 and skips
//  never-read arena arrays {2,18,22}.

typedef __attribute__((ext_vector_type(8))) short short8;
typedef __attribute__((ext_vector_type(4))) short short4v;
typedef __attribute__((ext_vector_type(4))) float float4v;
typedef __attribute__((ext_vector_type(2))) unsigned long long ull2;

#define BF2F(x) __bfloat162float(x)
typedef __hip_bfloat16 bf;

__device__ __forceinline__ float frcp(float x) {
  return __builtin_amdgcn_rcpf(x);
}
__device__ __forceinline__ float fsigmoid(float x) {
  return frcp(1.f + __expf(-x));
}
__device__ __forceinline__ float ftanh(float x) {
  // 1 - 2/(1+e^{2x}): saturates correctly (rcp(inf)=0 -> +1; e->0 -> -1)
  float e = __expf(2.f * x);
  return 1.f - 2.f * frcp(1.f + e);
}
__device__ __forceinline__ float rdv(const void* p, int i, int f) {
  return f ? ((const float*)p)[i] : BF2F(((const bf*)p)[i]);
}
__device__ __forceinline__ float upk(unsigned long long v, int s) {
  union { unsigned int i; float f; } x;
  x.i = ((unsigned int)((v >> s) & 0xffffULL)) << 16;
  return x.f;
}

// ---------------------------------------------------------------------------
static const int AO[23] = {
  0, 2097152, 4194304, 4685824, 4702208, 4702336, 4751488, 4800640, 4801024,
  4801408, 4899712, 4948864, 4949248, 4949632, 5047936, 5097088, 5097472,
  5097856, 5098368, 5098384, 5102480, 5106576, 5110160};
static const int AN[23] = {
  2097152, 2097152, 491520, 16384, 128, 49152, 49152, 384, 384, 98304, 49152,
  384, 384, 98304, 49152, 384, 384, 512, 2, 4096, 4096, 3584, 14};

struct CArgs {
  const void* src[23];
  int n[23];
  int off[23];
};

__global__ void kDetect(const unsigned short* __restrict__ p, int* flag) {
  __shared__ int s;
  if (threadIdx.x == 0) s = 0;
  __syncthreads();
  int hit = 0;
  for (int i = threadIdx.x; i < 4096; i += 1024) {
    int e = (p[i] >> 7) & 0xFF;
    if (e >= 0xC0) hit = 1;
  }
  if (hit) atomicOr(&s, 1);
  __syncthreads();
  if (threadIdx.x == 0) *flag = s;
}

// kConvert: y<23 = vectorized dtype-normalize into arena (skips raw-consumed
// arrays 2/18/22); y==23 = former kPrep, reading d_in directly via rdv.
__global__ void kConvert(CArgs a, const int* __restrict__ flag,
                         bf* __restrict__ arena,
                         const void* __restrict__ WqR, const void* __restrict__ WkR,
                         const void* __restrict__ W2R, const void* __restrict__ WcR,
                         bf* __restrict__ Wqk, bf* __restrict__ W2p,
                         bf* __restrict__ Wcb) {
  const int b = blockIdx.y;
  const int f = *flag;
  if (b == 23) {  // prep
    int idx = blockIdx.x * 256 + threadIdx.x;
    if (idx < 8192) {
      int r = idx >> 7, c = idx & 127;
      float v = (r < 32) ? rdv(WqR, r * 128 + c, f) : rdv(WkR, (r - 32) * 128 + c, f);
      Wqk[idx] = __float2bfloat16(v);
    }
    if (idx < 4096)
      W2p[idx] = __float2bfloat16((idx < 3584) ? rdv(W2R, idx, f) : 0.f);
    if (idx < 512) {
      int dir = idx >> 8, l = (idx >> 7) & 1, k = idx & 127;
      Wcb[idx] = __float2bfloat16(rdv(WcR, l * 256 + dir * 128 + k, f));
    }
    return;
  }
  if (b == 2 || b == 18 || b == 22) return;  // consumed raw via rdv
  const int n = a.n[b];
  const int nv = n & ~7;
  bf* dst = arena + a.off[b];
  const int gid = blockIdx.x * 256 + threadIdx.x;
  const int gs = gridDim.x * 256;
  if (f) {
    const float* s = (const float*)a.src[b];
    for (int i = gid * 8; i < nv; i += gs * 8) {
      float4 x0 = *(const float4*)(s + i);
      float4 x1 = *(const float4*)(s + i + 4);
      short8 v;
      bf t;
      t = __float2bfloat16(x0.x); v[0] = *(short*)&t;
      t = __float2bfloat16(x0.y); v[1] = *(short*)&t;
      t = __float2bfloat16(x0.z); v[2] = *(short*)&t;
      t = __float2bfloat16(x0.w); v[3] = *(short*)&t;
      t = __float2bfloat16(x1.x); v[4] = *(short*)&t;
      t = __float2bfloat16(x1.y); v[5] = *(short*)&t;
      t = __float2bfloat16(x1.z); v[6] = *(short*)&t;
      t = __float2bfloat16(x1.w); v[7] = *(short*)&t;
      *(short8*)(dst + i) = v;
    }
    for (int i = nv + gid; i < n; i += gs) dst[i] = __float2bfloat16(s[i]);
  } else {
    const short8* s = (const short8*)a.src[b];
    short8* d = (short8*)dst;
    for (int i = gid; i * 8 < nv; i += gs) d[i] = s[i];
    const unsigned short* ss = (const unsigned short*)a.src[b];
    unsigned short* ds = (unsigned short*)dst;
    for (int i = nv + gid; i < n; i += gs) ds[i] = ss[i];
  }
}

// ---------------------------------------------------------------------------
// kGemm: out[M x N](bf16) = A[M x 128] @ W[N x 128]^T + bias, optional relu.
__global__ __launch_bounds__(256) void kGemm(const bf* __restrict__ A,
                                             const bf* __restrict__ W,
                                             const bf* __restrict__ bias,
                                             bf* __restrict__ out,
                                             int N, int relu) {
  const int tid = threadIdx.x;
  const int wave = tid >> 6, lane = tid & 63;
  const int quad = lane >> 4, ci = lane & 15;
  const int mr = blockIdx.x * 64 + wave * 16;
  const int nbase = blockIdx.y * 64;
  const int ntiles = (N - nbase < 64) ? ((N - nbase) >> 4) : 4;

  float4v acc[4];
#pragma unroll
  for (int i = 0; i < 4; ++i) acc[i] = {0.f, 0.f, 0.f, 0.f};

#pragma unroll
  for (int ks = 0; ks < 4; ++ks) {
    short8 a = *(const short8*)(A + (size_t)(mr + ci) * 128 + ks * 32 + quad * 8);
    for (int nt = 0; nt < ntiles; ++nt) {
      short8 b = *(const short8*)(W + (size_t)(nbase + nt * 16 + ci) * 128 + ks * 32 + quad * 8);
      acc[nt] = __builtin_amdgcn_mfma_f32_16x16x32_bf16(a, b, acc[nt], 0, 0, 0);
    }
  }

  for (int nt = 0; nt < ntiles; ++nt) {
    int col = nbase + nt * 16 + ci;
    float bv = bias ? BF2F(bias[col]) : 0.f;
#pragma unroll
    for (int r = 0; r < 4; ++r) {
      int row = mr + quad * 4 + r;
      float v = acc[nt][r] + bv;
      if (relu) v = fmaxf(v, 0.f);
      out[(size_t)row * N + col] = __float2bfloat16(v);
    }
  }
}

// ---------------------------------------------------------------------------
// kStep: single GRU step (cell GRU only).
__global__ __launch_bounds__(256, 4) void kStep(
    const bf* __restrict__ Hp, const bf* __restrict__ Whh,
    const bf* __restrict__ G, int gld,
    const bf* __restrict__ bhh,
    bf* __restrict__ Ho, float* __restrict__ HcopyF) {
  const int half = blockIdx.z;
  const int tid = threadIdx.x;
  const int wave = tid >> 6, lane = tid & 63;
  const int quad = lane >> 4, ci = lane & 15;
  const int mr = blockIdx.x * 64 + wave * 16;

  float4v acc[12];
#pragma unroll
  for (int i = 0; i < 12; ++i) acc[i] = {0.f, 0.f, 0.f, 0.f};

#pragma unroll
  for (int ks = 0; ks < 4; ++ks) {
    short8 a = *(const short8*)(Hp + (size_t)(mr + ci) * 128 + ks * 32 + quad * 8);
#pragma unroll
    for (int g = 0; g < 3; ++g)
#pragma unroll
      for (int nt = 0; nt < 4; ++nt) {
        short8 b = *(const short8*)(Whh + (size_t)(g * 128 + half * 64 + nt * 16 + ci) * 128 + ks * 32 + quad * 8);
        acc[g * 4 + nt] = __builtin_amdgcn_mfma_f32_16x16x32_bf16(a, b, acc[g * 4 + nt], 0, 0, 0);
      }
  }

  float bR[4], bZ[4], bN[4];
#pragma unroll
  for (int nt = 0; nt < 4; ++nt) {
    int c = half * 64 + nt * 16 + ci;
    bR[nt] = BF2F(bhh[c]);
    bZ[nt] = BF2F(bhh[128 + c]);
    bN[nt] = BF2F(bhh[256 + c]);
  }

#pragma unroll
  for (int r = 0; r < 4; ++r) {
    int rr = mr + quad * 4 + r;
    const bf* gs = G + (size_t)rr * gld;
#pragma unroll
    for (int nt = 0; nt < 4; ++nt) {
      int c = half * 64 + nt * 16 + ci;
      float gr = BF2F(gs[c]), gz = BF2F(gs[128 + c]), gnn = BF2F(gs[256 + c]);
      float pre_r = acc[nt][r] + gr + bR[nt];
      float pre_z = acc[4 + nt][r] + gz + bZ[nt];
      float hn_   = acc[8 + nt][r] + bN[nt];
      float rg = fsigmoid(pre_r);
      float zg = fsigmoid(pre_z);
      float ng = ftanh(gnn + rg * hn_);
      float hp = BF2F(Hp[(size_t)rr * 128 + c]);
      float hv = ng + zg * (hp - ng);
      Ho[(size_t)rr * 128 + c] = __float2bfloat16(hv);
      if (HcopyF) HcopyF[(size_t)rr * 128 + c] = hv;
    }
  }
}

// ---------------------------------------------------------------------------
// kSeq v6: grid (1024, 2), 512 thr = 8 waves (nh = 16-col slice).
// Operand-SWAPPED MFMAs: D[hcol][batch]. Thread (quad,ci) owns batch=ci and
// hcols nh*16+quad*4+{0..3}:
//  - sH write: one ds_write_b64 (4 consecutive bf16) — conflict-free;
//  - sGiN read: 2x b128 at wave-uniform addr (broadcast);
//  - jr once per thread per step.
// Register contents of all frags identical to v5 (A/B layouts coincide);
// only mfma argument order + epilogue indexing changed -> bit-identical math.
__global__ __launch_bounds__(512, 4) void kSeq(
    const bf* __restrict__ hrnn,
    const bf* __restrict__ Wih_f, const bf* __restrict__ Wih_b,
    const bf* __restrict__ Whh_f, const bf* __restrict__ Whh_b,
    const bf* __restrict__ bih_f, const bf* __restrict__ bih_b,
    const bf* __restrict__ bhh_f, const bf* __restrict__ bhh_b,
    const bf* __restrict__ Wcb, float* __restrict__ L) {
  __shared__ unsigned long long sGiN[16][130];  // [batch][hcol] 3 bf16 gates
  __shared__ bf sH[2][16][136];                 // h ping-pong [batch][hcol]
  __shared__ float sL[16][15][2];               // logits [batch][m][logit]
  __shared__ bf sWc[2][136];                    // Wc rows for this dir

  const int env = blockIdx.x;
  const int dir = blockIdx.y;
  const int tid = threadIdx.x;
  const int wave = tid >> 6, lane = tid & 63;
  const int nh = wave;
  const int quad = lane >> 4, ci = lane & 15;
  const bf* Wih = dir ? Wih_b : Wih_f;
  const bf* Whh = dir ? Whh_b : Whh_f;
  const bf* bih = dir ? bih_b : bih_f;
  const bf* bhh = dir ? bhh_b : bhh_f;
  const int h0q = nh * 16 + quad * 4;           // this thread's hcol base

  // ---- Phase 1: gi GEMM (swapped: D[hcol][batch]) ----
  float4v gS[3], gN[3];
#pragma unroll
  for (int i = 0; i < 3; ++i) { gS[i] = {0.f, 0.f, 0.f, 0.f}; gN[i] = {0.f, 0.f, 0.f, 0.f}; }
#pragma unroll
  for (int ks = 0; ks < 4; ++ks) {
    short8 bh = *(const short8*)(hrnn + (size_t)(env * 16 + ci) * 128 + ks * 32 + quad * 8);
#pragma unroll
    for (int g = 0; g < 3; ++g) {
      const bf* wrow = Wih + (size_t)(g * 128 + nh * 16 + ci) * 256 + ks * 32 + quad * 8;
      short8 ws = *(const short8*)(wrow);
      short8 wn = *(const short8*)(wrow + 128);
      gS[g] = __builtin_amdgcn_mfma_f32_16x16x32_bf16(ws, bh, gS[g], 0, 0, 0);
      gN[g] = __builtin_amdgcn_mfma_f32_16x16x32_bf16(wn, bh, gN[g], 0, 0, 0);
    }
  }
  // fold bih (+bhh for r,z gates) into self-gi; now per-r (hcol = h0q + r)
#pragma unroll
  for (int g = 0; g < 3; ++g)
#pragma unroll
    for (int r = 0; r < 4; ++r) {
      int c = g * 128 + h0q + r;
      float bv = BF2F(bih[c]);
      if (g < 2) bv += BF2F(bhh[c]);
      gS[g][r] += bv;
    }
  // pack nbr-gi: sGiN[batch=ci][hcol=h0q+r]
#pragma unroll
  for (int r = 0; r < 4; ++r) {
    unsigned long long pk = 0;
#pragma unroll
    for (int g = 0; g < 3; ++g) {
      bf b = __float2bfloat16(gN[g][r]);
      pk |= ((unsigned long long)(*(unsigned short*)&b)) << (16 * g);
    }
    sGiN[ci][h0q + r] = pk;
  }

  // zero h buffer 0; fill sWc
  {
    bf z = __float2bfloat16(0.f);
    bf* p = &sH[0][0][0];
    for (int i = tid; i < 16 * 136; i += 512) p[i] = z;
    if (tid < 256)
      sWc[tid >> 7][tid & 127] = Wcb[(dir * 2 + (tid >> 7)) * 128 + (tid & 127)];
  }

  // ---- Phase 2: persistent Whh A-frags (48 VGPRs), constants ----
  short8 Bf[12];
#pragma unroll
  for (int g = 0; g < 3; ++g)
#pragma unroll
    for (int ks = 0; ks < 4; ++ks)
      Bf[g * 4 + ks] =
          *(const short8*)(Whh + (size_t)(g * 128 + nh * 16 + ci) * 128 + ks * 32 + quad * 8);

  float bNc[4];
#pragma unroll
  for (int r = 0; r < 4; ++r) bNc[r] = BF2F(bhh[256 + h0q + r]);

  // h_{t-1} for this thread's 4 slots (batch=ci, hcols h0q+r)
  float hPrev[4];
#pragma unroll
  for (int r = 0; r < 4; ++r) hPrev[r] = 0.f;

  __syncthreads();

  // ---- Phase 3: 15 steps ----
  for (int t = 0; t < 15; ++t) {
    const int cur = t & 1, nxt = cur ^ 1;
    const int m = dir ? (14 - t) : t;
    const int jr = m + ((m >= ci) ? 1 : 0);  // neighbor batch row for batch=ci

    // nbr-gi for this thread's 4 hcols (wave-uniform per quad -> broadcast)
    ull2 nb01 = *(const ull2*)&sGiN[jr][h0q];
    ull2 nb23 = *(const ull2*)&sGiN[jr][h0q + 2];

    float4v acc[3];
#pragma unroll
    for (int i = 0; i < 3; ++i) acc[i] = {0.f, 0.f, 0.f, 0.f};
    float4v lacc = {0.f, 0.f, 0.f, 0.f};
#pragma unroll
    for (int ks = 0; ks < 4; ++ks) {
      short8 bh = *(const short8*)&sH[cur][ci][ks * 32 + quad * 8];
#pragma unroll
      for (int g = 0; g < 3; ++g)
        acc[g] = __builtin_amdgcn_mfma_f32_16x16x32_bf16(Bf[g * 4 + ks], bh, acc[g], 0, 0, 0);
      if (nh == 0) {
        // A rows >=2 garbage -> D rows >=2 garbage (unread); rows 0,1 exact.
        short8 wv = *(const short8*)&sWc[ci & 1][ks * 32 + quad * 8];
        lacc = __builtin_amdgcn_mfma_f32_16x16x32_bf16(wv, bh, lacc, 0, 0, 0);
      }
    }
    if (nh == 0 && t > 0 && quad == 0) {
      int mp = dir ? (15 - t) : (t - 1);   // m of step t-1
      sL[ci][mp][0] = lacc[0];
      sL[ci][mp][1] = lacc[1];
    }

    short4v hv4;
#pragma unroll
    for (int r = 0; r < 4; ++r) {
      unsigned long long nb = (r == 0) ? nb01.x : (r == 1) ? nb01.y
                             : (r == 2) ? nb23.x : nb23.y;
      float pre_r = acc[0][r] + gS[0][r] + upk(nb, 0);
      float pre_z = acc[1][r] + gS[1][r] + upk(nb, 16);
      float gnn   = gS[2][r] + upk(nb, 32);
      float hn_   = acc[2][r] + bNc[r];
      float rg = fsigmoid(pre_r);
      float zg = fsigmoid(pre_z);
      float ng = ftanh(gnn + rg * hn_);
      float hv = ng + zg * (hPrev[r] - ng);
      hPrev[r] = hv;
      bf b = __float2bfloat16(hv);
      hv4[r] = *(short*)&b;
    }
    *(short4v*)&sH[nxt][ci][h0q] = hv4;  // one b64, conflict-free
    __syncthreads();
  }

  // tail: logits of h_14 (in sH[1])
  if (nh == 0) {
    float4v lacc = {0.f, 0.f, 0.f, 0.f};
#pragma unroll
    for (int ks = 0; ks < 4; ++ks) {
      short8 bh = *(const short8*)&sH[1][ci][ks * 32 + quad * 8];
      short8 wv = *(const short8*)&sWc[ci & 1][ks * 32 + quad * 8];
      lacc = __builtin_amdgcn_mfma_f32_16x16x32_bf16(wv, bh, lacc, 0, 0, 0);
    }
    if (quad == 0) {
      int mf = dir ? 0 : 14;
      sL[ci][mf][0] = lacc[0];
      sL[ci][mf][1] = lacc[1];
    }
  }
  __syncthreads();

  for (int i = tid; i < 480; i += 512) {
    int row = i / 30, rem = i - row * 30;
    int mm = rem >> 1, l = rem & 1;
    L[(size_t)((env * 16 + row) * 15 + mm) * 4 + dir * 2 + l] = sL[row][mm][l];
  }
}

// ---------------------------------------------------------------------------
// kAttn (fused): qk via in-block MFMA + gumbel hard_w + attention + agg.
__global__ __launch_bounds__(256) void kAttn(
    const bf* __restrict__ h, const bf* __restrict__ Wqk,
    const float* __restrict__ L, const void* __restrict__ guRaw,
    const void* __restrict__ bcRaw, const int* __restrict__ flag,
    bf* __restrict__ aggB) {
  __shared__ float sh[16 * 132];
  __shared__ float sqk[16 * 64];
  __shared__ float shw[16 * 15];
  __shared__ float sw[16 * 16];
  int bb = blockIdx.x, tid = threadIdx.x;
  const int f = *flag;

  // qk[16x64] = h[16x128] @ Wqk[64x128]^T, one 16-col tile per wave
  {
    const int w = tid >> 6, lane = tid & 63;
    const int quad = lane >> 4, ci = lane & 15;
    float4v acc = {0.f, 0.f, 0.f, 0.f};
#pragma unroll
    for (int ks = 0; ks < 4; ++ks) {
      short8 a_ = *(const short8*)(h + (size_t)(bb * 16 + ci) * 128 + ks * 32 + quad * 8);
      short8 b_ = *(const short8*)(Wqk + (size_t)(w * 16 + ci) * 128 + ks * 32 + quad * 8);
      acc = __builtin_amdgcn_mfma_f32_16x16x32_bf16(a_, b_, acc, 0, 0, 0);
    }
#pragma unroll
    for (int r = 0; r < 4; ++r)
      sqk[(quad * 4 + r) * 64 + w * 16 + ci] = acc[r];
  }
  for (int i = tid; i < 2048; i += 256)
    sh[(i >> 7) * 132 + (i & 127)] = BF2F(h[(size_t)bb * 2048 + i]);
  if (tid < 240) {  // gumbel hard_w (formerly kGumbel)
    int idx = bb * 240 + tid;
    const float* Lp = L + (size_t)idx * 4;
    float l0 = Lp[0] + Lp[2] + rdv(bcRaw, 0, f);
    float l1 = Lp[1] + Lp[3] + rdv(bcRaw, 1, f);
    float u0 = rdv(guRaw, idx * 2, f);
    float u1 = rdv(guRaw, idx * 2 + 1, f);
    float g0 = -__logf(-__logf(u0 + 1e-10f) + 1e-10f);
    float g1 = -__logf(-__logf(u1 + 1e-10f) + 1e-10f);
    shw[tid] = fsigmoid(((l1 + g1) - (l0 + g0)) * 2.0f);
  }
  __syncthreads();

  int a = tid >> 4, i = tid & 15;
  float s = -1e30f;
  if (i < 15) {
    int j = i + (i >= a);
    float d = 0.f;
#pragma unroll
    for (int c = 0; c < 32; ++c) d += sqk[a * 64 + c] * sqk[j * 64 + 32 + c];
    s = shw[a * 15 + i] * d * 0.17677669529663687f;
  }
  float mx = s;
#pragma unroll
  for (int d = 1; d < 16; d <<= 1) mx = fmaxf(mx, __shfl_xor(mx, d));
  float e = (i < 15) ? __expf(s - mx) : 0.f;
  float sum = e;
#pragma unroll
  for (int d = 1; d < 16; d <<= 1) sum += __shfl_xor(sum, d);
  float w = (i < 15) ? (e * frcp(sum)) * shw[a * 15 + i] : 0.f;
  sw[a * 16 + i] = w;
  __syncthreads();

  float ac[8] = {0, 0, 0, 0, 0, 0, 0, 0};
  for (int mm = 0; mm < 15; ++mm) {
    int jm = mm + (mm >= a);
    float wm = sw[a * 16 + mm];
    const float* shp = &sh[jm * 132 + i * 8];
    float4 h0 = *(const float4*)shp;
    float4 h1 = *(const float4*)(shp + 4);
    ac[0] += wm * h0.x; ac[1] += wm * h0.y; ac[2] += wm * h0.z; ac[3] += wm * h0.w;
    ac[4] += wm * h1.x; ac[5] += wm * h1.y; ac[6] += wm * h1.z; ac[7] += wm * h1.w;
  }
  short8 v;
#pragma unroll
  for (int d = 0; d < 8; ++d) {
    bf b = __float2bfloat16(ac[d]);
    v[d] = *(short*)&b;
  }
  *(short8*)(aggB + (size_t)(bb * 16 + a) * 128 + i * 8) = v;
}

// ---------------------------------------------------------------------------
// kGemmOut: out14[16384 x 14] (fp32) = [h_rnn, agg] @ W2p^T + b2.
__global__ __launch_bounds__(256) void kGemmOut(
    const bf* __restrict__ hrnn, const bf* __restrict__ aggB,
    const bf* __restrict__ W2p, const void* __restrict__ b2Raw,
    const int* __restrict__ flag, float* __restrict__ out) {
  const int tid = threadIdx.x;
  const int wave = tid >> 6, lane = tid & 63;
  const int quad = lane >> 4, ci = lane & 15;
  const int mr = blockIdx.x * 64 + wave * 16;
  const int f = *flag;

  float4v acc = {0.f, 0.f, 0.f, 0.f};
#pragma unroll
  for (int ks = 0; ks < 8; ++ks) {
    const bf* src = (ks < 4) ? hrnn : aggB;
    int k = (ks & 3) * 32 + quad * 8;
    short8 a = *(const short8*)(src + (size_t)(mr + ci) * 128 + k);
    short8 b = *(const short8*)(W2p + (size_t)ci * 256 + ks * 32 + quad * 8);
    acc = __builtin_amdgcn_mfma_f32_16x16x32_bf16(a, b, acc, 0, 0, 0);
  }

  if (ci < 14) {
    float bv = rdv(b2Raw, ci, f);
#pragma unroll
    for (int r = 0; r < 4; ++r)
      out[(size_t)(mr + quad * 4 + r) * 14 + ci] = acc[r] + bv;
  }
}

// ---------------------------------------------------------------------------
extern "C" void kernel_launch(void* const* d_in, const int* in_sizes, int n_in,
                              void* d_out, int out_size, void* d_ws, size_t ws_size,
                              hipStream_t stream) {
  const size_t OFF_ARENA = 0;          // bf16 arena; L (3.93MB) overlaps dead
                                       //   inputs+hidden [0, 8.38MB) after cell
  const size_t OFF_FLAG  = 10220544;
  const size_t OFF_A     = 10220800;   // x1+gi_c -> agg
  const size_t OFF_WQK   = 26998016;   // 16 KB
  const size_t OFF_WCB   = 27014400;   // 1 KB
  const size_t OFF_W2P   = 27410944;   // 8 KB
  const size_t OFF_HRNN  = 27419136;   // 4 MB
  const size_t NEEDED    = 84042240;
  if (ws_size < NEEDED) return;
  if (n_in < 23 || in_sizes[0] != 2097152 || in_sizes[3] != 16384 ||
      in_sizes[5] != 49152 || in_sizes[9] != 98304 || in_sizes[17] != 512 ||
      in_sizes[19] != 4096 || in_sizes[21] != 3584 || out_size != 2326528)
    return;

  char* ws = (char*)d_ws;
  bf*    arena = (bf*)(ws + OFF_ARENA);
  float* L     = (float*)(ws + OFF_ARENA);  // 3.93 MB; valid after cell GRU
  int*   flag  = (int*)(ws + OFF_FLAG);
  bf*    x1    = (bf*)(ws + OFF_A);
  bf*    gi_c  = (bf*)(ws + OFF_A + 4194304);
  bf*    aggB  = (bf*)(ws + OFF_A + 983040);
  bf*    Wqk   = (bf*)(ws + OFF_WQK);
  bf*    Wcb   = (bf*)(ws + OFF_WCB);
  bf*    W2p   = (bf*)(ws + OFF_W2P);
  bf*    hrnn  = (bf*)(ws + OFF_HRNN);

  float* out14 = (float*)d_out;
  float* outh  = (float*)d_out + 229376;

  kDetect<<<1, 1024, 0, stream>>>((const unsigned short*)d_in[0], flag);
  CArgs ca;
  for (int i = 0; i < 23; ++i) { ca.src[i] = d_in[i]; ca.n[i] = AN[i]; ca.off[i] = AO[i]; }
  kConvert<<<dim3(128, 24), 256, 0, stream>>>(ca, flag, arena,
                                              d_in[19], d_in[20], d_in[21], d_in[17],
                                              Wqk, W2p, Wcb);

  const bf* inputs = arena + AO[0];
  const bf* hidden = arena + AO[1];
  const bf* W1     = arena + AO[3];
  const bf* b1     = arena + AO[4];
  const bf* Wih_c  = arena + AO[5];
  const bf* Whh_c  = arena + AO[6];
  const bf* bih_c  = arena + AO[7];
  const bf* bhh_c  = arena + AO[8];
  const bf* Wih_f  = arena + AO[9];
  const bf* Whh_f  = arena + AO[10];
  const bf* bih_f  = arena + AO[11];
  const bf* bhh_f  = arena + AO[12];
  const bf* Wih_b  = arena + AO[13];
  const bf* Whh_b  = arena + AO[14];
  const bf* bih_b  = arena + AO[15];
  const bf* bhh_b  = arena + AO[16];

  kGemm<<<dim3(256, 2), 256, 0, stream>>>(inputs, W1, b1, x1, 128, 1);
  kGemm<<<dim3(256, 6), 256, 0, stream>>>(x1, Wih_c, bih_c, gi_c, 384, 0);
  // cell GRU: h_rnn (bf16 + fp32 copy to d_out)
  kStep<<<dim3(256, 1, 2), 256, 0, stream>>>(hidden, Whh_c, gi_c, 384, bhh_c,
                                             hrnn, outh);

  // fused gi-GEMM + 15-step bidirectional GRU -> L
  kSeq<<<dim3(1024, 2), 512, 0, stream>>>(hrnn, Wih_f, Wih_b, Whh_f, Whh_b,
                                          bih_f, bih_b, bhh_f, bhh_b, Wcb, L);

  // fused qk + gumbel + attention
  kAttn<<<dim3(1024), 256, 0, stream>>>(hrnn, Wqk, L, d_in[2], d_in[18], flag,
                                        aggB);
  kGemmOut<<<dim3(256), 256, 0, stream>>>(hrnn, aggB, W2p, d_in[22], flag, out14);
}